// Round 5
// baseline (5209.641 us; speedup 1.0000x reference)
//
#include <hip/hip_runtime.h>
#include <math.h>

typedef _Float16 half2_t __attribute__((ext_vector_type(2)));

static constexpr int HID   = 1024;  // hidden size
static constexpr int NGRP  = 16;    // chunk groups (fp16 weight replicas fit 16x)
static constexpr int GPB   = 16;    // blocks per group; block owns 64 units, wave owns 16
static constexpr int WARM  = 96;    // warmup steps re-deriving state from h=0
static constexpr int NTHR  = 256;   // 4 waves; 1 wave/SIMD -> 512 unified VGPR cap
static constexpr int PCOLS = 96;    // K_MIX*3*IN_DIM

__device__ __forceinline__ float sigmoid_f(float x) { return 1.0f / (1.0f + __expf(-x)); }

__device__ __forceinline__ float dot2h(half2_t a, half2_t b, float c) {
#if __has_builtin(__builtin_amdgcn_fdot2)
  return __builtin_amdgcn_fdot2(a, b, c, false);
#else
  unsigned ua = __builtin_bit_cast(unsigned, a);
  unsigned ub = __builtin_bit_cast(unsigned, b);
  asm("v_dot2_f32_f16 %0, %1, %2, %0" : "+v"(c) : "v"(ua), "v"(ub));
  return c;
#endif
}

// Fold 16 accumulators while reducing across 64 lanes.
// Returns, in lane l, the full 64-lane sum of a[l & 15].
__device__ __forceinline__ float reduce16(const float a[16], int l) {
  const bool m1 = l & 1, m2 = l & 2, m4 = l & 4, m8 = l & 8;
  float b[8];
#pragma unroll
  for (int i = 0; i < 8; ++i)
    b[i] = (m1 ? a[2*i+1] : a[2*i]) + __shfl_xor((m1 ? a[2*i] : a[2*i+1]), 1, 64);
  float c[4];
#pragma unroll
  for (int i = 0; i < 4; ++i)
    c[i] = (m2 ? b[2*i+1] : b[2*i]) + __shfl_xor((m2 ? b[2*i] : b[2*i+1]), 2, 64);
  float d[2];
#pragma unroll
  for (int i = 0; i < 2; ++i)
    d[i] = (m4 ? c[2*i+1] : c[2*i]) + __shfl_xor((m4 ? c[2*i] : c[2*i+1]), 4, 64);
  float e = (m8 ? d[1] : d[0]) + __shfl_xor((m8 ? d[0] : d[1]), 8, 64);
  e += __shfl_xor(e, 16, 64);
  e += __shfl_xor(e, 32, 64);
  return e;
}

__global__ __launch_bounds__(NTHR, 1)
void gru_wavesync(const float* __restrict__ ex,   // [T,8]
                  const float* __restrict__ Wx,   // [8,3072]
                  const float* __restrict__ Wh,   // [1024,3072]
                  const float* __restrict__ bx,   // [3072]
                  const float* __restrict__ bh,   // [3072]
                  const float* __restrict__ Wd,   // [1024,96]
                  const float* __restrict__ bd,   // [96]
                  float* __restrict__ out,        // [T,96]
                  unsigned* __restrict__ pkt,     // [NGRP][2][HID] 4B packets {fp16 h | tag16}, zeroed
                  int T)
{
  const int g   = blockIdx.x & 15;   // group
  const int p   = blockIdx.x >> 4;   // block within group, 0..15
  const int tid = threadIdx.x;
  const int w   = tid >> 6;          // wave 0..3
  const int l   = tid & 63;          // lane

  unsigned* gpk = pkt + (size_t)g * (2 * HID);

  const int LCH         = T / NGRP;               // 512
  const int chunk_begin = g * LCH;
  const int s0          = (g == 0) ? 0 : (chunk_begin - WARM);
  const int n_local     = (chunk_begin + LCH) - s0;  // 512 or 608

  __shared__ unsigned wd_s[6 * 512];  // 6 out-proj columns, fp16-pair packed

  // ---- Wh slice in registers (fp16 pairs): wave owns units colbase..colbase+15
  const int colbase = 64 * p + 16 * w;
  half2_t whp[16][3][8];
#pragma unroll
  for (int u = 0; u < 16; ++u)
#pragma unroll
    for (int gt = 0; gt < 3; ++gt)
#pragma unroll
      for (int m = 0; m < 8; ++m) {
        const int r0 = 2 * l + 128 * m;
        const size_t col = (size_t)gt * HID + colbase + u;
        half2_t wv;
        wv.x = (_Float16)Wh[(size_t)r0 * 3072 + col];
        wv.y = (_Float16)Wh[(size_t)(r0 + 1) * 3072 + col];
        whp[u][gt][m] = wv;
      }

  // finalize constants for unit myu = colbase + (l&15) (lanes 0..15 finalize)
  const int myu = colbase + (l & 15);
  float wxz[8], wxr_[8], wxc[8];
#pragma unroll
  for (int i = 0; i < 8; ++i) {
    wxz[i]  = Wx[i * 3072 + 0 * HID + myu];
    wxr_[i] = Wx[i * 3072 + 1 * HID + myu];
    wxc[i]  = Wx[i * 3072 + 2 * HID + myu];
  }
  const float bz  = bx[0 * HID + myu] + bh[0 * HID + myu];  // merged (pre-sigmoid adds)
  const float br  = bx[1 * HID + myu] + bh[1 * HID + myu];
  const float bxc = bx[2 * HID + myu];
  const float bhc = bh[2 * HID + myu];                      // stays inside r*(...)

  // out-projection: waves 0..2 own 2 columns each; Wd fp16-packed in LDS
  const float bdv0 = (w < 3) ? bd[6 * p + 2 * w + 0] : 0.f;
  const float bdv1 = (w < 3) ? bd[6 * p + 2 * w + 1] : 0.f;
  for (int idx = tid; idx < 6 * 512; idx += NTHR) {
    const int cl = idx >> 9, pr = idx & 511;
    const int col = 6 * p + cl;
    half2_t wv;
    wv.x = (_Float16)Wd[(size_t)(2 * pr) * PCOLS + col];
    wv.y = (_Float16)Wd[(size_t)(2 * pr + 1) * PCOLS + col];
    wd_s[idx] = __builtin_bit_cast(unsigned, wv);
  }
  __syncthreads();  // the ONLY barrier; loop below is wave-self-synchronized

  float hold = 0.f;  // this lane's unit state (fp32 recurrence path)

  for (int j = 0; j <= n_local; ++j) {
    const int t = s0 + j;  // global step consumed this iteration

    // teacher-forced input (issued early; consumed by lanes 0..15)
    float4 xv0 = {0, 0, 0, 0}, xv1 = {0, 0, 0, 0};
    if (j < n_local && t >= 1) {
      const float4* ep = (const float4*)(ex + (size_t)(t - 1) * 8);
      xv0 = ep[0];
      xv1 = ep[1];
    }

    // poll this lane's 8 row-pairs (tag j); data IS the flag; no barrier, no LDS
    const unsigned* base = gpk + (size_t)(j & 1) * HID;
    unsigned long long v[8];
#pragma unroll
    for (int m = 0; m < 8; ++m)
      v[m] = __hip_atomic_load((const unsigned long long*)(base + 2 * l + 128 * m),
                               __ATOMIC_RELAXED, __HIP_MEMORY_SCOPE_AGENT);
    half2_t hh[8];
    const unsigned jt = (unsigned)(j & 0xFFFF);
#pragma unroll
    for (int m = 0; m < 8; ++m) {
      while ((unsigned)(v[m] & 0xFFFF) != jt || (unsigned)((v[m] >> 32) & 0xFFFF) != jt)
        v[m] = __hip_atomic_load((const unsigned long long*)(base + 2 * l + 128 * m),
                                 __ATOMIC_RELAXED, __HIP_MEMORY_SCOPE_AGENT);
      const unsigned hw = (unsigned)((v[m] >> 16) & 0xFFFFu) | (unsigned)((v[m] >> 48) << 16);
      hh[m] = __builtin_bit_cast(half2_t, hw);
    }

    if (j < n_local) {
      float a[16], sz, sr, sc;
#pragma unroll
      for (int u = 0; u < 16; ++u) a[u] = 0.f;
#pragma unroll
      for (int m = 0; m < 8; ++m)
#pragma unroll
        for (int u = 0; u < 16; ++u) a[u] = dot2h(whp[u][0][m], hh[m], a[u]);
      sz = reduce16(a, l);
#pragma unroll
      for (int u = 0; u < 16; ++u) a[u] = 0.f;
#pragma unroll
      for (int m = 0; m < 8; ++m)
#pragma unroll
        for (int u = 0; u < 16; ++u) a[u] = dot2h(whp[u][1][m], hh[m], a[u]);
      sr = reduce16(a, l);
#pragma unroll
      for (int u = 0; u < 16; ++u) a[u] = 0.f;
#pragma unroll
      for (int m = 0; m < 8; ++m)
#pragma unroll
        for (int u = 0; u < 16; ++u) a[u] = dot2h(whp[u][2][m], hh[m], a[u]);
      sc = reduce16(a, l);

      if (l < 16) {
        float gz = 0.f, gr = 0.f, gc = 0.f;
        gz = fmaf(xv0.x, wxz[0], gz);  gz = fmaf(xv0.y, wxz[1], gz);
        gz = fmaf(xv0.z, wxz[2], gz);  gz = fmaf(xv0.w, wxz[3], gz);
        gz = fmaf(xv1.x, wxz[4], gz);  gz = fmaf(xv1.y, wxz[5], gz);
        gz = fmaf(xv1.z, wxz[6], gz);  gz = fmaf(xv1.w, wxz[7], gz);
        gr = fmaf(xv0.x, wxr_[0], gr); gr = fmaf(xv0.y, wxr_[1], gr);
        gr = fmaf(xv0.z, wxr_[2], gr); gr = fmaf(xv0.w, wxr_[3], gr);
        gr = fmaf(xv1.x, wxr_[4], gr); gr = fmaf(xv1.y, wxr_[5], gr);
        gr = fmaf(xv1.z, wxr_[6], gr); gr = fmaf(xv1.w, wxr_[7], gr);
        gc = fmaf(xv0.x, wxc[0], gc);  gc = fmaf(xv0.y, wxc[1], gc);
        gc = fmaf(xv0.z, wxc[2], gc);  gc = fmaf(xv0.w, wxc[3], gc);
        gc = fmaf(xv1.x, wxc[4], gc);  gc = fmaf(xv1.y, wxc[5], gc);
        gc = fmaf(xv1.z, wxc[6], gc);  gc = fmaf(xv1.w, wxc[7], gc);

        // Keras GRU reset_after=True, gate order (z, r, h)
        const float z    = sigmoid_f(gz + sz + bz);
        const float r    = sigmoid_f(gr + sr + br);
        const float cand = tanhf(gc + bxc + r * (sc + bhc));
        const float hnew = z * hold + (1.f - z) * cand;
        hold = hnew;

        const unsigned short hb = __builtin_bit_cast(unsigned short, (_Float16)hnew);
        const unsigned pv = ((unsigned)hb << 16) | (unsigned)((j + 1) & 0xFFFF);
        __hip_atomic_store(gpk + (size_t)(((j + 1) & 1) * HID + myu), pv,
                           __ATOMIC_RELAXED, __HIP_MEMORY_SCOPE_AGENT);
      }
    }

    // fused output row t-1 (hh = hs[t-1]); after the store => off the serial chain
    if (w < 3) {
      const int tp = t - 1;
      if (tp >= chunk_begin) {
        float ap0 = 0.f, ap1 = 0.f;
#pragma unroll
        for (int m = 0; m < 8; ++m) {
          const int pr = 64 * m + l;
          ap0 = dot2h(hh[m], __builtin_bit_cast(half2_t, wd_s[(2 * w + 0) * 512 + pr]), ap0);
          ap1 = dot2h(hh[m], __builtin_bit_cast(half2_t, wd_s[(2 * w + 1) * 512 + pr]), ap1);
        }
#pragma unroll
        for (int mm = 32; mm; mm >>= 1) {
          ap0 += __shfl_xor(ap0, mm, 64);
          ap1 += __shfl_xor(ap1, mm, 64);
        }
        if (l == 0) {
          out[(size_t)tp * PCOLS + 6 * p + 2 * w + 0] = ap0 + bdv0;
          out[(size_t)tp * PCOLS + 6 * p + 2 * w + 1] = ap1 + bdv1;
        }
      }
    }
  }
}

extern "C" void kernel_launch(void* const* d_in, const int* in_sizes, int n_in,
                              void* d_out, int out_size, void* d_ws, size_t ws_size,
                              hipStream_t stream)
{
  const float* ex = (const float*)d_in[0];
  const float* Wx = (const float*)d_in[1];
  const float* Wh = (const float*)d_in[2];
  const float* bx = (const float*)d_in[3];
  const float* bh = (const float*)d_in[4];
  const float* Wd = (const float*)d_in[5];
  const float* bd = (const float*)d_in[6];
  float* out = (float*)d_out;
  unsigned* pkt = (unsigned*)d_ws;
  const int T = in_sizes[0] / 8;

  // zero packets: tag 0 + fp16 h=0 == valid initial state for every group
  hipMemsetAsync(d_ws, 0, (size_t)NGRP * 2 * HID * sizeof(unsigned), stream);
  hipLaunchKernelGGL(gru_wavesync, dim3(NGRP * GPB), dim3(NTHR), 0, stream,
                     ex, Wx, Wh, bx, bh, Wd, bd, out, pkt, T);
}

// Round 6
// 3492.674 us; speedup vs baseline: 1.4916x; 1.4916x over previous
//
#include <hip/hip_runtime.h>
#include <math.h>

typedef _Float16 half2_t __attribute__((ext_vector_type(2)));

static constexpr int HID   = 1024;  // hidden size
static constexpr int NGRP  = 16;    // chunk groups (fp16 weight replicas fit 16x)
static constexpr int GPB   = 16;    // blocks per group; block owns 64 units, wave owns 16
static constexpr int WARM  = 96;    // warmup steps re-deriving state from h=0
static constexpr int NTHR  = 256;   // 4 waves; 1 wave/SIMD -> 512 unified VGPR cap
static constexpr int PCOLS = 96;    // K_MIX*3*IN_DIM

__device__ __forceinline__ float rcp_fast(float x) { return __builtin_amdgcn_rcpf(x); }
__device__ __forceinline__ float sigmoid_f(float x) { return rcp_fast(1.0f + __expf(-x)); }
__device__ __forceinline__ float tanh_f(float x) {
  const float t = __expf(-2.0f * x);
  return (1.0f - t) * rcp_fast(1.0f + t);
}

__device__ __forceinline__ float dot2h(half2_t a, half2_t b, float c) {
#if __has_builtin(__builtin_amdgcn_fdot2)
  return __builtin_amdgcn_fdot2(a, b, c, false);
#else
  unsigned ua = __builtin_bit_cast(unsigned, a);
  unsigned ub = __builtin_bit_cast(unsigned, b);
  asm("v_dot2_f32_f16 %0, %1, %2, %0" : "+v"(c) : "v"(ua), "v"(ub));
  return c;
#endif
}

// Fold 16 accumulators while reducing across 64 lanes.
// Returns, in lane l, the full 64-lane sum of a[l & 15].
__device__ __forceinline__ float reduce16(const float a[16], int l) {
  const bool m1 = l & 1, m2 = l & 2, m4 = l & 4, m8 = l & 8;
  float b[8];
#pragma unroll
  for (int i = 0; i < 8; ++i)
    b[i] = (m1 ? a[2*i+1] : a[2*i]) + __shfl_xor((m1 ? a[2*i] : a[2*i+1]), 1, 64);
  float c[4];
#pragma unroll
  for (int i = 0; i < 4; ++i)
    c[i] = (m2 ? b[2*i+1] : b[2*i]) + __shfl_xor((m2 ? b[2*i] : b[2*i+1]), 2, 64);
  float d[2];
#pragma unroll
  for (int i = 0; i < 2; ++i)
    d[i] = (m4 ? c[2*i+1] : c[2*i]) + __shfl_xor((m4 ? c[2*i] : c[2*i+1]), 4, 64);
  float e = (m8 ? d[1] : d[0]) + __shfl_xor((m8 ? d[0] : d[1]), 8, 64);
  e += __shfl_xor(e, 16, 64);
  e += __shfl_xor(e, 32, 64);
  return e;
}

__global__ __launch_bounds__(NTHR, 1)
void gru_blockpoll(const float* __restrict__ ex,   // [T,8]
                   const float* __restrict__ Wx,   // [8,3072]
                   const float* __restrict__ Wh,   // [1024,3072]
                   const float* __restrict__ bx,   // [3072]
                   const float* __restrict__ bh,   // [3072]
                   const float* __restrict__ Wd,   // [1024,96]
                   const float* __restrict__ bd,   // [96]
                   float* __restrict__ out,        // [T,96]
                   unsigned* __restrict__ pkt,     // [NGRP][2][HID] packets {fp16 h | tag16}, zeroed
                   int T)
{
  const int g   = blockIdx.x & 15;   // group (blocks of a group share an XCD under round-robin)
  const int p   = blockIdx.x >> 4;   // block within group, 0..15
  const int tid = threadIdx.x;
  const int w   = tid >> 6;          // wave 0..3
  const int l   = tid & 63;          // lane

  unsigned* gpk = pkt + (size_t)g * (2 * HID);

  const int LCH         = T / NGRP;               // 512
  const int chunk_begin = g * LCH;
  const int s0          = (g == 0) ? 0 : (chunk_begin - WARM);
  const int n_local     = (chunk_begin + LCH) - s0;  // 512 or 608

  __shared__ unsigned pk_s[2][HID];   // parity-double-buffered staged packets (8 KB)
  __shared__ unsigned wd_s[6 * 512];  // 6 out-proj columns, fp16-pair packed (12 KB)

  // ---- Wh slice in registers (fp16 pairs): wave owns units colbase..colbase+15
  const int colbase = 64 * p + 16 * w;
  half2_t whp[16][3][8];
#pragma unroll
  for (int u = 0; u < 16; ++u)
#pragma unroll
    for (int gt = 0; gt < 3; ++gt)
#pragma unroll
      for (int m = 0; m < 8; ++m) {
        const int r0 = 2 * l + 128 * m;
        const size_t col = (size_t)gt * HID + colbase + u;
        half2_t wv;
        wv.x = (_Float16)Wh[(size_t)r0 * 3072 + col];
        wv.y = (_Float16)Wh[(size_t)(r0 + 1) * 3072 + col];
        whp[u][gt][m] = wv;
      }

  // finalize constants for unit myu = colbase + (l&15) (lanes 0..15 finalize)
  const int myu = colbase + (l & 15);
  float wxz[8], wxr_[8], wxc[8];
#pragma unroll
  for (int i = 0; i < 8; ++i) {
    wxz[i]  = Wx[i * 3072 + 0 * HID + myu];
    wxr_[i] = Wx[i * 3072 + 1 * HID + myu];
    wxc[i]  = Wx[i * 3072 + 2 * HID + myu];
  }
  const float bz  = bx[0 * HID + myu] + bh[0 * HID + myu];  // merged pre-sigmoid biases
  const float br  = bx[1 * HID + myu] + bh[1 * HID + myu];
  const float bxc = bx[2 * HID + myu];
  const float bhc = bh[2 * HID + myu];                      // stays inside r*(...)

  // out-projection: waves 0..2 own 2 columns each; Wd fp16-packed in LDS
  const float bdv0 = (w < 3) ? bd[6 * p + 2 * w + 0] : 0.f;
  const float bdv1 = (w < 3) ? bd[6 * p + 2 * w + 1] : 0.f;
  for (int idx = tid; idx < 6 * 512; idx += NTHR) {
    const int cl = idx >> 9, pr = idx & 511;
    const int col = 6 * p + cl;
    half2_t wv;
    wv.x = (_Float16)Wd[(size_t)(2 * pr) * PCOLS + col];
    wv.y = (_Float16)Wd[(size_t)(2 * pr + 1) * PCOLS + col];
    wd_s[idx] = __builtin_bit_cast(unsigned, wv);
  }
  __syncthreads();

  float hold = 0.f;  // this lane's unit state (fp32 recurrence path)

  for (int j = 0; j <= n_local; ++j) {
    const int t = s0 + j;  // global step consumed this iteration

    // teacher-forced input (issued early; consumed by lanes 0..15 in finalize)
    float4 xv0 = {0, 0, 0, 0}, xv1 = {0, 0, 0, 0};
    if (j < n_local && t >= 1) {
      const float4* ep = (const float4*)(ex + (size_t)(t - 1) * 8);
      xv0 = ep[0];
      xv1 = ep[1];
    }

    // block-cooperative poll: 256 threads x 4 slots, 1x traffic, throttled spin
    {
      const unsigned* base = gpk + (size_t)(j & 1) * HID;
      const unsigned jt = (unsigned)(j & 0xFFFF);
#pragma unroll
      for (int q = 0; q < 4; ++q) {
        const int slot = tid + (q << 8);
        unsigned v = __hip_atomic_load(base + slot, __ATOMIC_RELAXED, __HIP_MEMORY_SCOPE_AGENT);
        while ((v & 0xFFFFu) != jt) {
          __builtin_amdgcn_s_sleep(1);
          v = __hip_atomic_load(base + slot, __ATOMIC_RELAXED, __HIP_MEMORY_SCOPE_AGENT);
        }
        pk_s[j & 1][slot] = v;
      }
    }
    __syncthreads();  // the only barrier per step (LDS is parity-double-buffered)

    // unpack this lane's 8 row-pairs from LDS
    half2_t hh[8];
#pragma unroll
    for (int m = 0; m < 8; ++m) {
      const uint2 pp = *(const uint2*)&pk_s[j & 1][2 * l + 128 * m];
      const unsigned hw = (pp.x >> 16) | (pp.y & 0xFFFF0000u);
      hh[m] = __builtin_bit_cast(half2_t, hw);
    }

    if (j < n_local) {
      float a[16], sz, sr, sc;
#pragma unroll
      for (int u = 0; u < 16; ++u) a[u] = 0.f;
#pragma unroll
      for (int m = 0; m < 8; ++m)
#pragma unroll
        for (int u = 0; u < 16; ++u) a[u] = dot2h(whp[u][0][m], hh[m], a[u]);
      sz = reduce16(a, l);
#pragma unroll
      for (int u = 0; u < 16; ++u) a[u] = 0.f;
#pragma unroll
      for (int m = 0; m < 8; ++m)
#pragma unroll
        for (int u = 0; u < 16; ++u) a[u] = dot2h(whp[u][1][m], hh[m], a[u]);
      sr = reduce16(a, l);
#pragma unroll
      for (int u = 0; u < 16; ++u) a[u] = 0.f;
#pragma unroll
      for (int m = 0; m < 8; ++m)
#pragma unroll
        for (int u = 0; u < 16; ++u) a[u] = dot2h(whp[u][2][m], hh[m], a[u]);
      sc = reduce16(a, l);

      if (l < 16) {
        float gz = 0.f, gr = 0.f, gc = 0.f;
        gz = fmaf(xv0.x, wxz[0], gz);  gz = fmaf(xv0.y, wxz[1], gz);
        gz = fmaf(xv0.z, wxz[2], gz);  gz = fmaf(xv0.w, wxz[3], gz);
        gz = fmaf(xv1.x, wxz[4], gz);  gz = fmaf(xv1.y, wxz[5], gz);
        gz = fmaf(xv1.z, wxz[6], gz);  gz = fmaf(xv1.w, wxz[7], gz);
        gr = fmaf(xv0.x, wxr_[0], gr); gr = fmaf(xv0.y, wxr_[1], gr);
        gr = fmaf(xv0.z, wxr_[2], gr); gr = fmaf(xv0.w, wxr_[3], gr);
        gr = fmaf(xv1.x, wxr_[4], gr); gr = fmaf(xv1.y, wxr_[5], gr);
        gr = fmaf(xv1.z, wxr_[6], gr); gr = fmaf(xv1.w, wxr_[7], gr);
        gc = fmaf(xv0.x, wxc[0], gc);  gc = fmaf(xv0.y, wxc[1], gc);
        gc = fmaf(xv0.z, wxc[2], gc);  gc = fmaf(xv0.w, wxc[3], gc);
        gc = fmaf(xv1.x, wxc[4], gc);  gc = fmaf(xv1.y, wxc[5], gc);
        gc = fmaf(xv1.z, wxc[6], gc);  gc = fmaf(xv1.w, wxc[7], gc);

        // Keras GRU reset_after=True, gate order (z, r, h)
        const float z    = sigmoid_f(gz + sz + bz);
        const float r    = sigmoid_f(gr + sr + br);
        const float cand = tanh_f(gc + bxc + r * (sc + bhc));
        const float hnew = z * hold + (1.f - z) * cand;
        hold = hnew;

        const unsigned short hb = __builtin_bit_cast(unsigned short, (_Float16)hnew);
        const unsigned pv = ((unsigned)hb << 16) | (unsigned)((j + 1) & 0xFFFF);
        __hip_atomic_store(gpk + (size_t)(((j + 1) & 1) * HID + myu), pv,
                           __ATOMIC_RELAXED, __HIP_MEMORY_SCOPE_AGENT);
      }
    }

    // fused output row t-1 (hh = hs[t-1]); after the store => off the serial chain
    if (w < 3) {
      const int tp = t - 1;
      if (tp >= chunk_begin) {
        float ap0 = 0.f, ap1 = 0.f;
#pragma unroll
        for (int m = 0; m < 8; ++m) {
          const int pr = 64 * m + l;
          ap0 = dot2h(hh[m], __builtin_bit_cast(half2_t, wd_s[(2 * w + 0) * 512 + pr]), ap0);
          ap1 = dot2h(hh[m], __builtin_bit_cast(half2_t, wd_s[(2 * w + 1) * 512 + pr]), ap1);
        }
#pragma unroll
        for (int mm = 32; mm; mm >>= 1) {
          ap0 += __shfl_xor(ap0, mm, 64);
          ap1 += __shfl_xor(ap1, mm, 64);
        }
        if (l == 0) {
          out[(size_t)tp * PCOLS + 6 * p + 2 * w + 0] = ap0 + bdv0;
          out[(size_t)tp * PCOLS + 6 * p + 2 * w + 1] = ap1 + bdv1;
        }
      }
    }
  }
}

extern "C" void kernel_launch(void* const* d_in, const int* in_sizes, int n_in,
                              void* d_out, int out_size, void* d_ws, size_t ws_size,
                              hipStream_t stream)
{
  const float* ex = (const float*)d_in[0];
  const float* Wx = (const float*)d_in[1];
  const float* Wh = (const float*)d_in[2];
  const float* bx = (const float*)d_in[3];
  const float* bh = (const float*)d_in[4];
  const float* Wd = (const float*)d_in[5];
  const float* bd = (const float*)d_in[6];
  float* out = (float*)d_out;
  unsigned* pkt = (unsigned*)d_ws;
  const int T = in_sizes[0] / 8;

  // zero packets: tag 0 + fp16 h=0 == valid initial state for every group
  hipMemsetAsync(d_ws, 0, (size_t)NGRP * 2 * HID * sizeof(unsigned), stream);
  hipLaunchKernelGGL(gru_blockpoll, dim3(NGRP * GPB), dim3(NTHR), 0, stream,
                     ex, Wx, Wh, bx, bh, Wd, bd, out, pkt, T);
}

// Round 7
// 2689.838 us; speedup vs baseline: 1.9368x; 1.2985x over previous
//
#include <hip/hip_runtime.h>
#include <math.h>

typedef _Float16 half2_t __attribute__((ext_vector_type(2)));

static constexpr int HID   = 1024;  // hidden size
static constexpr int NGRP  = 16;    // chunk groups (fp16 weight replicas fit 16x)
static constexpr int GPB   = 16;    // blocks per group; block owns 64 units, wave owns 16
static constexpr int WARM  = 48;    // warmup steps re-deriving state from h=0 (0.55^48 ~ 3e-13)
static constexpr int NTHR  = 256;   // 4 waves; 1 wave/SIMD -> 512 unified VGPR cap
static constexpr int PCOLS = 96;    // K_MIX*3*IN_DIM

__device__ __forceinline__ float rcp_fast(float x) { return __builtin_amdgcn_rcpf(x); }
__device__ __forceinline__ float sigmoid_f(float x) { return rcp_fast(1.0f + __expf(-x)); }
__device__ __forceinline__ float tanh_f(float x) {
  const float t = __expf(-2.0f * x);
  return (1.0f - t) * rcp_fast(1.0f + t);
}

__device__ __forceinline__ float dot2h(half2_t a, half2_t b, float c) {
#if __has_builtin(__builtin_amdgcn_fdot2)
  return __builtin_amdgcn_fdot2(a, b, c, false);
#else
  unsigned ua = __builtin_bit_cast(unsigned, a);
  unsigned ub = __builtin_bit_cast(unsigned, b);
  asm("v_dot2_f32_f16 %0, %1, %2, %0" : "+v"(c) : "v"(ua), "v"(ub));
  return c;
#endif
}

// Fold 16 accumulators while reducing across 64 lanes.
// Returns, in lane l, the full 64-lane sum of a[l & 15].
__device__ __forceinline__ float reduce16(const float a[16], int l) {
  const bool m1 = l & 1, m2 = l & 2, m4 = l & 4, m8 = l & 8;
  float b[8];
#pragma unroll
  for (int i = 0; i < 8; ++i)
    b[i] = (m1 ? a[2*i+1] : a[2*i]) + __shfl_xor((m1 ? a[2*i] : a[2*i+1]), 1, 64);
  float c[4];
#pragma unroll
  for (int i = 0; i < 4; ++i)
    c[i] = (m2 ? b[2*i+1] : b[2*i]) + __shfl_xor((m2 ? b[2*i] : b[2*i+1]), 2, 64);
  float d[2];
#pragma unroll
  for (int i = 0; i < 2; ++i)
    d[i] = (m4 ? c[2*i+1] : c[2*i]) + __shfl_xor((m4 ? c[2*i] : c[2*i+1]), 4, 64);
  float e = (m8 ? d[1] : d[0]) + __shfl_xor((m8 ? d[0] : d[1]), 8, 64);
  e += __shfl_xor(e, 16, 64);
  e += __shfl_xor(e, 32, 64);
  return e;
}

__global__ __launch_bounds__(NTHR, 1)
void gru_pkt8(const float* __restrict__ ex,   // [T,8]
              const float* __restrict__ Wx,   // [8,3072]
              const float* __restrict__ Wh,   // [1024,3072]
              const float* __restrict__ bx,   // [3072]
              const float* __restrict__ bh,   // [3072]
              const float* __restrict__ Wd,   // [1024,96]
              const float* __restrict__ bd,   // [96]
              float* __restrict__ out,        // [T,96]
              unsigned long long* __restrict__ pkt, // [NGRP][2][512] packets {2xfp16 | tag32}, zeroed
              int T)
{
  const int g   = blockIdx.x & 15;   // group
  const int p   = blockIdx.x >> 4;   // block within group, 0..15
  const int tid = threadIdx.x;
  const int w   = tid >> 6;          // wave 0..3
  const int l   = tid & 63;          // lane

  unsigned long long* gpk = pkt + (size_t)g * 1024;  // [2][512]

  const int LCH         = T / NGRP;               // 512
  const int chunk_begin = g * LCH;
  const int s0          = (g == 0) ? 0 : (chunk_begin - WARM);
  const int n_local     = (chunk_begin + LCH) - s0;  // 512 or 560

  __shared__ unsigned pk_s[2][512];   // parity-double-buffered h-pairs (4 KB)
  __shared__ unsigned wd_s[6 * 512];  // 6 out-proj columns, fp16-pair packed (12 KB)

  // ---- Wh slice in registers (fp16 pairs): wave owns units colbase..colbase+15
  const int colbase = 64 * p + 16 * w;
  half2_t whp[16][3][8];
#pragma unroll
  for (int u = 0; u < 16; ++u)
#pragma unroll
    for (int gt = 0; gt < 3; ++gt)
#pragma unroll
      for (int m = 0; m < 8; ++m) {
        const int r0 = 2 * l + 128 * m;
        const size_t col = (size_t)gt * HID + colbase + u;
        half2_t wv;
        wv.x = (_Float16)Wh[(size_t)r0 * 3072 + col];
        wv.y = (_Float16)Wh[(size_t)(r0 + 1) * 3072 + col];
        whp[u][gt][m] = wv;
      }

  // finalize constants for unit myu = colbase + (l&15) (lanes 0..15 finalize)
  const int myu = colbase + (l & 15);
  float wxz[8], wxr_[8], wxc[8];
#pragma unroll
  for (int i = 0; i < 8; ++i) {
    wxz[i]  = Wx[i * 3072 + 0 * HID + myu];
    wxr_[i] = Wx[i * 3072 + 1 * HID + myu];
    wxc[i]  = Wx[i * 3072 + 2 * HID + myu];
  }
  const float bz  = bx[0 * HID + myu] + bh[0 * HID + myu];  // merged pre-sigmoid biases
  const float br  = bx[1 * HID + myu] + bh[1 * HID + myu];
  const float bxc = bx[2 * HID + myu];
  const float bhc = bh[2 * HID + myu];                      // stays inside r*(...)

  // out-projection: waves 0..2 own 2 columns each; Wd fp16-packed in LDS
  const float bdv0 = (w < 3) ? bd[6 * p + 2 * w + 0] : 0.f;
  const float bdv1 = (w < 3) ? bd[6 * p + 2 * w + 1] : 0.f;
  for (int idx = tid; idx < 6 * 512; idx += NTHR) {
    const int cl = idx >> 9, pr = idx & 511;
    const int col = 6 * p + cl;
    half2_t wv;
    wv.x = (_Float16)Wd[(size_t)(2 * pr) * PCOLS + col];
    wv.y = (_Float16)Wd[(size_t)(2 * pr + 1) * PCOLS + col];
    wd_s[idx] = __builtin_bit_cast(unsigned, wv);
  }
  __syncthreads();

  float hold = 0.f;  // this lane's unit state (fp32 recurrence path)

  for (int j = 0; j <= n_local; ++j) {
    const int t = s0 + j;  // global step consumed this iteration

    // teacher-forced input (issued early; latency overlaps the poll)
    float4 xv0 = {0, 0, 0, 0}, xv1 = {0, 0, 0, 0};
    if (j < n_local && t >= 1) {
      const float4* ep = (const float4*)(ex + (size_t)(t - 1) * 8);
      xv0 = ep[0];
      xv1 = ep[1];
    }

    // poll: 2 packets/thread, BOTH issued before verifying (1 round-trip detection)
    {
      const unsigned long long* base = gpk + (size_t)(j & 1) * 512;
      const unsigned ju = (unsigned)j;
      unsigned long long v0 = __hip_atomic_load(base + tid,       __ATOMIC_RELAXED, __HIP_MEMORY_SCOPE_AGENT);
      unsigned long long v1 = __hip_atomic_load(base + tid + 256, __ATOMIC_RELAXED, __HIP_MEMORY_SCOPE_AGENT);
      while ((unsigned)v0 != ju) {
        __builtin_amdgcn_s_sleep(1);
        v0 = __hip_atomic_load(base + tid, __ATOMIC_RELAXED, __HIP_MEMORY_SCOPE_AGENT);
      }
      while ((unsigned)v1 != ju) {
        __builtin_amdgcn_s_sleep(1);
        v1 = __hip_atomic_load(base + tid + 256, __ATOMIC_RELAXED, __HIP_MEMORY_SCOPE_AGENT);
      }
      pk_s[j & 1][tid]       = (unsigned)(v0 >> 32);
      pk_s[j & 1][tid + 256] = (unsigned)(v1 >> 32);
    }

    // Wx projection off the critical path (fills straggler wait before barrier)
    float gz = 0.f, gr = 0.f, gc = 0.f;
    gz = fmaf(xv0.x, wxz[0], gz);  gz = fmaf(xv0.y, wxz[1], gz);
    gz = fmaf(xv0.z, wxz[2], gz);  gz = fmaf(xv0.w, wxz[3], gz);
    gz = fmaf(xv1.x, wxz[4], gz);  gz = fmaf(xv1.y, wxz[5], gz);
    gz = fmaf(xv1.z, wxz[6], gz);  gz = fmaf(xv1.w, wxz[7], gz);
    gr = fmaf(xv0.x, wxr_[0], gr); gr = fmaf(xv0.y, wxr_[1], gr);
    gr = fmaf(xv0.z, wxr_[2], gr); gr = fmaf(xv0.w, wxr_[3], gr);
    gr = fmaf(xv1.x, wxr_[4], gr); gr = fmaf(xv1.y, wxr_[5], gr);
    gr = fmaf(xv1.z, wxr_[6], gr); gr = fmaf(xv1.w, wxr_[7], gr);
    gc = fmaf(xv0.x, wxc[0], gc);  gc = fmaf(xv0.y, wxc[1], gc);
    gc = fmaf(xv0.z, wxc[2], gc);  gc = fmaf(xv0.w, wxc[3], gc);
    gc = fmaf(xv1.x, wxc[4], gc);  gc = fmaf(xv1.y, wxc[5], gc);
    gc = fmaf(xv1.z, wxc[6], gc);  gc = fmaf(xv1.w, wxc[7], gc);

    __syncthreads();  // the only barrier per step (LDS is parity-double-buffered)

    // unpack this lane's 8 row-pairs from LDS (conflict-free: consecutive dwords)
    half2_t hh[8];
#pragma unroll
    for (int m = 0; m < 8; ++m)
      hh[m] = __builtin_bit_cast(half2_t, pk_s[j & 1][l + 64 * m]);

    if (j < n_local) {
      // gate-parallel dots: 3 independent accumulator sets -> reduce trees interleave
      float az[16], ar[16], ac[16];
#pragma unroll
      for (int u = 0; u < 16; ++u) { az[u] = 0.f; ar[u] = 0.f; ac[u] = 0.f; }
#pragma unroll
      for (int m = 0; m < 8; ++m)
#pragma unroll
        for (int u = 0; u < 16; ++u) {
          az[u] = dot2h(whp[u][0][m], hh[m], az[u]);
          ar[u] = dot2h(whp[u][1][m], hh[m], ar[u]);
          ac[u] = dot2h(whp[u][2][m], hh[m], ac[u]);
        }
      const float sz = reduce16(az, l);
      const float sr = reduce16(ar, l);
      const float sc = reduce16(ac, l);

      if (l < 16) {
        // Keras GRU reset_after=True, gate order (z, r, h)
        const float z    = sigmoid_f(gz + sz + bz);
        const float r    = sigmoid_f(gr + sr + br);
        const float cand = tanh_f(gc + bxc + r * (sc + bhc));
        const float hnew = z * hold + (1.f - z) * cand;
        hold = hnew;

        // pack 2 units/packet: even lane gathers partner's fp16 via 1 shfl, stores 8B
        const unsigned short hb = __builtin_bit_cast(unsigned short, (_Float16)hnew);
        const unsigned hi = (unsigned)__shfl((int)hb, l | 1, 64);
        if ((l & 1) == 0) {
          const unsigned pair = ((hi & 0xFFFFu) << 16) | (unsigned)hb;
          const unsigned long long pv = ((unsigned long long)pair << 32) | (unsigned)(j + 1);
          __hip_atomic_store(gpk + (size_t)(((j + 1) & 1) * 512 + ((colbase + l) >> 1)), pv,
                             __ATOMIC_RELAXED, __HIP_MEMORY_SCOPE_AGENT);
        }
      }
    }

    // fused output row t-1 (hh = hs[t-1]); after the store => off the serial chain
    if (w < 3) {
      const int tp = t - 1;
      if (tp >= chunk_begin) {
        float ap0 = 0.f, ap1 = 0.f;
#pragma unroll
        for (int m = 0; m < 8; ++m) {
          const int pr = 64 * m + l;
          ap0 = dot2h(hh[m], __builtin_bit_cast(half2_t, wd_s[(2 * w + 0) * 512 + pr]), ap0);
          ap1 = dot2h(hh[m], __builtin_bit_cast(half2_t, wd_s[(2 * w + 1) * 512 + pr]), ap1);
        }
#pragma unroll
        for (int mm = 32; mm; mm >>= 1) {
          ap0 += __shfl_xor(ap0, mm, 64);
          ap1 += __shfl_xor(ap1, mm, 64);
        }
        if (l == 0) {
          out[(size_t)tp * PCOLS + 6 * p + 2 * w + 0] = ap0 + bdv0;
          out[(size_t)tp * PCOLS + 6 * p + 2 * w + 1] = ap1 + bdv1;
        }
      }
    }
  }
}

extern "C" void kernel_launch(void* const* d_in, const int* in_sizes, int n_in,
                              void* d_out, int out_size, void* d_ws, size_t ws_size,
                              hipStream_t stream)
{
  const float* ex = (const float*)d_in[0];
  const float* Wx = (const float*)d_in[1];
  const float* Wh = (const float*)d_in[2];
  const float* bx = (const float*)d_in[3];
  const float* bh = (const float*)d_in[4];
  const float* Wd = (const float*)d_in[5];
  const float* bd = (const float*)d_in[6];
  float* out = (float*)d_out;
  unsigned long long* pkt = (unsigned long long*)d_ws;
  const int T = in_sizes[0] / 8;

  // zero packets: tag 0 + fp16 h=0 == valid initial state for every group
  hipMemsetAsync(d_ws, 0, (size_t)NGRP * 1024 * sizeof(unsigned long long), stream);
  hipLaunchKernelGGL(gru_pkt8, dim3(NGRP * GPB), dim3(NTHR), 0, stream,
                     ex, Wx, Wh, bx, bh, Wd, bd, out, pkt, T);
}